// Round 1
// baseline (2312.439 us; speedup 1.0000x reference)
//
#include <hip/hip_runtime.h>
#include <math.h>

#define BB 4
#define CC 64
#define HH 192
#define WW 192
#define HW (HH*WW)          // 36864
#define HID 128
#define USZ (BB*CC*HW)      // 9437184

__device__ __forceinline__ float gelu_exact(float x) {
    return 0.5f * x * (1.0f + erff(x * 0.70710678118654752f));
}
__device__ __forceinline__ float softplus_f(float x) { return log1pf(expf(x)); }
__device__ __forceinline__ float sigmoid_f(float x) { return 1.0f / (1.0f + expf(-x)); }

__device__ __forceinline__ float stencil5(const float* __restrict__ up, int y, int x, int d, float center) {
    float s = -4.0f * center;
    if (y >= d)      s += up[(y - d) * WW + x];
    if (y + d < HH)  s += up[(y + d) * WW + x];
    if (x >= d)      s += up[y * WW + x - d];
    if (x + d < WW)  s += up[y * WW + x + d];
    return s;
}

__global__ void zero_kernel(float* __restrict__ p, int n) {
    int i = blockIdx.x * 256 + threadIdx.x;
    if (i < n) p[i] = 0.0f;
}

// prev_probe[b,c,8,8] = 24x24 means of u
__global__ void probe0_kernel(const float* __restrict__ u, float* __restrict__ prev_probe) {
    int bx = blockIdx.x;                 // b*64+c
    const float* ub = u + (size_t)bx * HW;
    int tid = threadIdx.x, lane = tid & 63, w = tid >> 6;
    for (int j = 0; j < 16; ++j) {
        int cell = w * 16 + j;
        int py = cell >> 3, cx = cell & 7;
        float s = 0.0f;
        #pragma unroll
        for (int k = 0; k < 9; ++k) {
            int q = lane + 64 * k;
            int yy = py * 24 + q / 24;
            int xx = cx * 24 + q % 24;
            s += ub[yy * WW + xx];
        }
        #pragma unroll
        for (int off = 1; off < 64; off <<= 1) s += __shfl_xor(s, off);
        if (lane == 0) prev_probe[bx * 64 + cell] = s * (1.0f / 576.0f);
    }
}

// pooled[b,c] (global mean) and local_pool[b,c,4,4] (48x48 means)
__global__ void reduce_kernel(const float* __restrict__ u, float* __restrict__ pooled,
                              float* __restrict__ local_pool) {
    int bx = blockIdx.x;                 // b*64+c
    const float* ub = u + (size_t)bx * HW;
    int tid = threadIdx.x, lane = tid & 63, w = tid >> 6;
    __shared__ float cs[16];
    for (int j = 0; j < 4; ++j) {
        int cell = w * 4 + j;
        int cy = cell >> 2, cx = cell & 3;
        float s = 0.0f;
        #pragma unroll 4
        for (int k = 0; k < 36; ++k) {
            int q = lane + 64 * k;
            int yy = cy * 48 + q / 48;
            int xx = cx * 48 + q % 48;
            s += ub[yy * WW + xx];
        }
        #pragma unroll
        for (int off = 1; off < 64; off <<= 1) s += __shfl_xor(s, off);
        if (lane == 0) cs[cell] = s;
    }
    __syncthreads();
    if (tid < 16) local_pool[bx * 16 + tid] = cs[tid] * (1.0f / 2304.0f);
    if (tid == 0) {
        float t = 0.0f;
        #pragma unroll
        for (int i = 0; i < 16; ++i) t += cs[i];
        pooled[bx] = t * (1.0f / 36864.0f);
    }
}

// h_state update + 1x1 conv on local_pool -> localc[b,c,16]
__global__ void state_kernel(const float* __restrict__ pooled, const float* __restrict__ local_pool,
                             const float* __restrict__ gate_w, const float* __restrict__ gate_b,
                             const float* __restrict__ value_w, const float* __restrict__ value_b,
                             const float* __restrict__ local_w, const float* __restrict__ local_b,
                             float* __restrict__ h_state, float* __restrict__ localc) {
    int b = blockIdx.x, tid = threadIdx.x;
    __shared__ float ps[64];
    __shared__ float lp[1024];
    if (tid < 64) ps[tid] = pooled[b * 64 + tid];
    #pragma unroll
    for (int j = 0; j < 4; ++j) lp[tid + 256 * j] = local_pool[b * 1024 + tid + 256 * j];
    __syncthreads();
    if (tid < 64) {
        float g = gate_b[tid], v = value_b[tid];
        #pragma unroll 8
        for (int k = 0; k < 64; ++k) {
            float p = ps[k];
            g += p * gate_w[k * 64 + tid];
            v += p * value_w[k * 64 + tid];
        }
        h_state[b * 64 + tid] += sigmoid_f(g) * tanhf(v);
    }
    #pragma unroll
    for (int j = 0; j < 4; ++j) {
        int idx = tid + 256 * j;
        int co = idx >> 4, cell = idx & 15;
        float a = local_b[co];
        #pragma unroll 8
        for (int ci = 0; ci < 64; ++ci) a += local_w[co * 64 + ci] * lp[ci * 16 + cell];
        localc[b * 1024 + idx] = a;
    }
}

// fused step: Laplacian + MLP + du + (norm) + probe/energy accumulation
__global__ __launch_bounds__(256) void main_kernel(
    const float* __restrict__ u_src, float* __restrict__ u_dst,
    const float* __restrict__ w1, const float* __restrict__ b1,
    const float* __restrict__ w2, const float* __restrict__ b2,
    const float* __restrict__ h_state, const float* __restrict__ localc,
    const float* __restrict__ norm_w,
    const float* __restrict__ p_ag, const float* __restrict__ p_al,
    const float* __restrict__ p_logdt, const float* __restrict__ diff_w,
    float* __restrict__ probe_acc, float* __restrict__ accs, int do_norm) {
    __shared__ float X[64 * 64];         // [c][px]
    __shared__ float hid[64 * 129];      // [px][h] padded
    __shared__ float lc[64 * 16];
    __shared__ float plds[64 * 8];
    __shared__ float red[4 * 64];
    __shared__ float rsum[8];

    const int tid = threadIdx.x;
    const int px = tid & 63;
    const int cg = __builtin_amdgcn_readfirstlane(tid >> 6);
    const int b = blockIdx.z;
    const int y = blockIdx.y;
    const int x0 = blockIdx.x * 64;
    const int x = x0 + px;

    const float* ub = u_src + (size_t)b * CC * HW;

    #pragma unroll
    for (int i = 0; i < 16; ++i) {
        int idx = tid + 256 * i;           // idx = c*64 + xx
        int c = idx >> 6, xx = idx & 63;
        X[idx] = ub[c * HW + y * WW + x0 + xx];
    }
    #pragma unroll
    for (int i = 0; i < 4; ++i) {
        int idx = tid + 256 * i;
        lc[idx] = localc[b * 1024 + idx];
    }
    plds[tid] = 0.0f;
    plds[tid + 256] = 0.0f;
    __syncthreads();

    float dt = expf(p_logdt[0]);
    dt = fminf(fmaxf(dt, 0.005f), 0.35f);
    const float a_g = softplus_f(p_ag[0]);
    const float a_l = softplus_f(p_al[0]);
    const float dw0 = diff_w[0], dw1 = diff_w[1], dw2 = diff_w[2];

    const int cbase = cg * 16;

    // Laplacian, c = cbase + i
    float dif[16];
    #pragma unroll
    for (int i = 0; i < 16; ++i) {
        int c = cbase + i;
        const float* up = ub + c * HW;
        float center = X[c * 64 + px];
        float l1 = stencil5(up, y, x, 1, center);
        float l4 = stencil5(up, y, x, 4, center);
        float l16 = stencil5(up, y, x, 16, center);
        dif[i] = 0.25f * (dw0 * l1 + dw1 * l4 + dw2 * l16);
    }

    // MLP layer 1: hid[px][h], h = cg*32 + i
    const int hbase = cg * 32;
    float hacc[32];
    #pragma unroll
    for (int i = 0; i < 32; ++i) hacc[i] = 0.0f;
    #pragma unroll 4
    for (int k = 0; k < 64; ++k) {
        float xv = X[k * 64 + px];
        #pragma unroll
        for (int i = 0; i < 32; ++i) hacc[i] += xv * w1[k * HID + hbase + i];
    }
    #pragma unroll
    for (int i = 0; i < 32; ++i)
        hid[px * 129 + hbase + i] = gelu_exact(hacc[i] + b1[hbase + i]);
    __syncthreads();

    // MLP layer 2: out[px][co], co = cg*16 + i
    float racc[16];
    #pragma unroll
    for (int i = 0; i < 16; ++i) racc[i] = 0.0f;
    #pragma unroll 8
    for (int h = 0; h < HID; ++h) {
        float hv = hid[px * 129 + h];
        #pragma unroll
        for (int i = 0; i < 16; ++i) racc[i] += hv * w2[h * CC + cbase + i];
    }

    // bilinear upsample weights (in_size=4, out 192)
    float srcy = (y + 0.5f) * (1.0f / 48.0f) - 0.5f;
    srcy = fminf(fmaxf(srcy, 0.0f), 3.0f);
    int iy0 = (int)srcy; iy0 = min(iy0, 3);
    float ty = srcy - (float)iy0;
    int iy1 = min(iy0 + 1, 3);
    float srcx = (x + 0.5f) * (1.0f / 48.0f) - 0.5f;
    srcx = fminf(fmaxf(srcx, 0.0f), 3.0f);
    int jx0 = (int)srcx; jx0 = min(jx0, 3);
    float tx = srcx - (float)jx0;
    int jx1 = min(jx0 + 1, 3);
    const float wy0 = 1.0f - ty, wy1 = ty, wx0 = 1.0f - tx, wx1 = tx;
    const int pcy = y / 24;
    const int pcx = x / 24;

    float sum_du = 0.0f, sum_df = 0.0f, csq = 0.0f;
    float candv[16];
    #pragma unroll
    for (int i = 0; i < 16; ++i) {
        int c = cbase + i;
        float react = racc[i] + b2[c];
        float hs = h_state[b * CC + c];
        const float* L = lc + c * 16;
        float upv = wy0 * (wx0 * L[iy0 * 4 + jx0] + wx1 * L[iy0 * 4 + jx1]) +
                    wy1 * (wx0 * L[iy1 * 4 + jx0] + wx1 * L[iy1 * 4 + jx1]);
        float du = dif[i] + react + a_g * hs + a_l * upv;
        float cand = X[c * 64 + px] + dt * du;
        candv[i] = cand;
        sum_du += fabsf(du);
        sum_df += fabsf(dif[i]);
        csq += cand * cand;
        // probe partial: 8-lane segment sums (24-boundaries are 8-aligned)
        float v = cand;
        v += __shfl_xor(v, 1);
        v += __shfl_xor(v, 2);
        v += __shfl_xor(v, 4);
        if ((px & 7) == 0) atomicAdd(&plds[c * 8 + pcx], v);
    }

    float rinv = 1.0f;
    if (do_norm) {
        red[cg * 64 + px] = csq;
        __syncthreads();
        float tot = red[px] + red[64 + px] + red[128 + px] + red[192 + px];
        rinv = 1.0f / sqrtf(tot * (1.0f / 64.0f) + 1e-8f);
    }

    float* db = u_dst + (size_t)b * CC * HW;
    #pragma unroll
    for (int i = 0; i < 16; ++i) {
        int c = cbase + i;
        float o = candv[i];
        if (do_norm) o = o * rinv * norm_w[c];
        db[c * HW + y * WW + x] = o;
    }

    // block-wide |du|,|diff| sums
    #pragma unroll
    for (int off = 1; off < 64; off <<= 1) {
        sum_du += __shfl_xor(sum_du, off);
        sum_df += __shfl_xor(sum_df, off);
    }
    if ((tid & 63) == 0) { rsum[cg] = sum_du; rsum[4 + cg] = sum_df; }
    __syncthreads();
    if (tid == 0) {
        atomicAdd(&accs[0], rsum[0] + rsum[1] + rsum[2] + rsum[3]);
        atomicAdd(&accs[1], rsum[4] + rsum[5] + rsum[6] + rsum[7]);
    }
    // probe flush
    const int cmin = x0 / 24, cmax = (x0 + 63) / 24;
    for (int j = tid; j < 512; j += 256) {
        int c = j >> 3, cell = j & 7;
        if (cell >= cmin && cell <= cmax) {
            atomicAdd(&probe_acc[(b * CC + c) * 64 + pcy * 8 + cell], plds[j]);
        }
    }
}

__global__ void turb_kernel(float* __restrict__ prev_probe, float* __restrict__ probe_acc,
                            float* __restrict__ accs, float* __restrict__ d_scal, int step) {
    int tid = threadIdx.x;
    float s1 = 0.0f, s2 = 0.0f;
    for (int j = tid; j < 16384; j += 256) {
        float cur = probe_acc[j] * (1.0f / 576.0f);
        float pv = prev_probe[j];
        s1 += fabsf(cur - pv);
        s2 += fabsf(pv);
        prev_probe[j] = cur;
        probe_acc[j] = 0.0f;
    }
    __shared__ float sh[8];
    #pragma unroll
    for (int off = 1; off < 64; off <<= 1) {
        s1 += __shfl_xor(s1, off);
        s2 += __shfl_xor(s2, off);
    }
    int w = tid >> 6;
    if ((tid & 63) == 0) { sh[w] = s1; sh[4 + w] = s2; }
    __syncthreads();
    if (tid == 0) {
        s1 = sh[0] + sh[1] + sh[2] + sh[3];
        s2 = sh[4] + sh[5] + sh[6] + sh[7];
        float se = accs[0] * (1.0f / 9437184.0f);
        float le = accs[1] * (1.0f / 9437184.0f);
        float stop = (s1 * (1.0f / 16384.0f)) / (s2 * (1.0f / 16384.0f) + 1e-8f);
        float dturb = stop + 0.05f * se + 0.01f * le;
        float dsum = accs[2] + dturb;
        float ssum = accs[3] + se;
        accs[2] = dsum;
        accs[3] = ssum;
        accs[0] = 0.0f;
        accs[1] = 0.0f;
        if (step == 5) {
            d_scal[0] = dsum * (1.0f / 6.0f);
            d_scal[1] = ssum * (1.0f / 6.0f);
        }
    }
}

extern "C" void kernel_launch(void* const* d_in, const int* in_sizes, int n_in,
                              void* d_out, int out_size, void* d_ws, size_t ws_size,
                              hipStream_t stream) {
    const float* u_in    = (const float*)d_in[0];
    const float* w1      = (const float*)d_in[1];
    const float* b1      = (const float*)d_in[2];
    const float* w2      = (const float*)d_in[3];
    const float* b2      = (const float*)d_in[4];
    const float* gate_w  = (const float*)d_in[5];
    const float* gate_b  = (const float*)d_in[6];
    const float* value_w = (const float*)d_in[7];
    const float* value_b = (const float*)d_in[8];
    const float* norm_w  = (const float*)d_in[9];
    const float* local_w = (const float*)d_in[10];
    const float* local_b = (const float*)d_in[11];
    const float* p_ag    = (const float*)d_in[12];
    const float* p_al    = (const float*)d_in[13];
    const float* p_logdt = (const float*)d_in[14];
    const float* diff_w  = (const float*)d_in[15];

    float* ws = (float*)d_ws;
    float* uA         = ws;                       // USZ
    float* pooled     = ws + USZ;                 // 256
    float* local_pool = pooled + 256;             // 4096
    float* localc     = local_pool + 4096;        // 4096
    float* prev_probe = localc + 4096;            // 16384
    float* h_state    = prev_probe + 16384;       // 256   (zero region start)
    float* probe_acc  = h_state + 256;            // 16384
    float* accs       = probe_acc + 16384;        // 4

    float* uout   = (float*)d_out;
    float* d_scal = uout + USZ;

    zero_kernel<<<66, 256, 0, stream>>>(h_state, 256 + 16384 + 4);
    probe0_kernel<<<256, 256, 0, stream>>>(u_in, prev_probe);

    const float* src = u_in;
    for (int s = 0; s < 6; ++s) {
        float* dst = (s & 1) ? uout : uA;
        reduce_kernel<<<256, 256, 0, stream>>>(src, pooled, local_pool);
        state_kernel<<<4, 256, 0, stream>>>(pooled, local_pool, gate_w, gate_b, value_w,
                                            value_b, local_w, local_b, h_state, localc);
        main_kernel<<<dim3(3, HH, BB), 256, 0, stream>>>(
            src, dst, w1, b1, w2, b2, h_state, localc, norm_w,
            p_ag, p_al, p_logdt, diff_w, probe_acc, accs, (s & 1));
        turb_kernel<<<1, 256, 0, stream>>>(prev_probe, probe_acc, accs, d_scal, s);
        src = dst;
    }
}

// Round 4
// 2063.218 us; speedup vs baseline: 1.1208x; 1.1208x over previous
//
#include <hip/hip_runtime.h>
#include <math.h>

#define BB 4
#define CC 64
#define HH 192
#define WW 192
#define HW (HH*WW)          // 36864
#define HID 128
#define USZ (BB*CC*HW)      // 9437184

__device__ __forceinline__ float gelu_exact(float x) {
    return 0.5f * x * (1.0f + erff(x * 0.70710678118654752f));
}
__device__ __forceinline__ float softplus_f(float x) { return log1pf(expf(x)); }
__device__ __forceinline__ float sigmoid_f(float x) { return 1.0f / (1.0f + expf(-x)); }

__device__ __forceinline__ unsigned short f2bf(float f) {
    unsigned int u = __float_as_uint(f);
    unsigned int r = (u + 0x7fffu + ((u >> 16) & 1u)) >> 16;
    return (unsigned short)r;
}
__device__ __forceinline__ float bf2f(unsigned int bits16) {
    return __uint_as_float(bits16 << 16);
}

__device__ __forceinline__ float stencil5(const float* __restrict__ up, int y, int x, int d, float center) {
    float s = -4.0f * center;
    if (y >= d)      s += up[(y - d) * WW + x];
    if (y + d < HH)  s += up[(y + d) * WW + x];
    if (x >= d)      s += up[y * WW + x - d];
    if (x + d < WW)  s += up[y * WW + x + d];
    return s;
}

__global__ void zero_kernel(float* __restrict__ p, int n) {
    int i = blockIdx.x * 256 + threadIdx.x;
    if (i < n) p[i] = 0.0f;
}

// prev_probe[b,c,8,8] = 24x24 means of u
__global__ void probe0_kernel(const float* __restrict__ u, float* __restrict__ prev_probe) {
    int bx = blockIdx.x;                 // b*64+c
    const float* ub = u + (size_t)bx * HW;
    int tid = threadIdx.x, lane = tid & 63, w = tid >> 6;
    for (int j = 0; j < 16; ++j) {
        int cell = w * 16 + j;
        int py = cell >> 3, cx = cell & 7;
        float s = 0.0f;
        #pragma unroll
        for (int k = 0; k < 9; ++k) {
            int q = lane + 64 * k;
            int yy = py * 24 + q / 24;
            int xx = cx * 24 + q % 24;
            s += ub[yy * WW + xx];
        }
        #pragma unroll
        for (int off = 1; off < 64; off <<= 1) s += __shfl_xor(s, off);
        if (lane == 0) prev_probe[bx * 64 + cell] = s * (1.0f / 576.0f);
    }
}

// raw 48x48 sums of u_in -> local_acc[b,c,4,4]  (only for step 0)
__global__ void reduce0_kernel(const float* __restrict__ u, float* __restrict__ local_acc) {
    int bx = blockIdx.x;                 // b*64+c
    const float* ub = u + (size_t)bx * HW;
    int tid = threadIdx.x, lane = tid & 63, w = tid >> 6;
    __shared__ float cs[16];
    for (int j = 0; j < 4; ++j) {
        int cell = w * 4 + j;
        int cy = cell >> 2, cx = cell & 3;
        float s = 0.0f;
        #pragma unroll 4
        for (int k = 0; k < 36; ++k) {
            int q = lane + 64 * k;
            int yy = cy * 48 + q / 48;
            int xx = cx * 48 + q % 48;
            s += ub[yy * WW + xx];
        }
        #pragma unroll
        for (int off = 1; off < 64; off <<= 1) s += __shfl_xor(s, off);
        if (lane == 0) cs[cell] = s;
    }
    __syncthreads();
    if (tid < 16) local_acc[bx * 16 + tid] = cs[tid];
}

// glue: blocks 0-3 = state update for batch b (consumes local_acc sums),
//       block 4    = turbulence stats for the PREVIOUS step
__global__ void glue_kernel(const float* __restrict__ gate_w, const float* __restrict__ gate_b,
                            const float* __restrict__ value_w, const float* __restrict__ value_b,
                            const float* __restrict__ local_w, const float* __restrict__ local_b,
                            float* __restrict__ h_state, float* __restrict__ localc,
                            float* __restrict__ local_acc, float* __restrict__ prev_probe,
                            float* __restrict__ probe_acc, float* __restrict__ accs,
                            float* __restrict__ d_scal, int do_state, int do_turb, int step) {
    int blk = blockIdx.x, tid = threadIdx.x;
    __shared__ float lp[1024];
    __shared__ float ps[64];
    __shared__ float sh[8];
    if (blk == 4) {
        if (!do_turb) return;
        float s1 = 0.0f, s2 = 0.0f;
        for (int j = tid; j < 16384; j += 256) {
            float cur = probe_acc[j] * (1.0f / 576.0f);
            float pv = prev_probe[j];
            s1 += fabsf(cur - pv);
            s2 += fabsf(pv);
            prev_probe[j] = cur;
            probe_acc[j] = 0.0f;
        }
        #pragma unroll
        for (int off = 1; off < 64; off <<= 1) {
            s1 += __shfl_xor(s1, off);
            s2 += __shfl_xor(s2, off);
        }
        int w = tid >> 6;
        if ((tid & 63) == 0) { sh[w] = s1; sh[4 + w] = s2; }
        __syncthreads();
        if (tid == 0) {
            s1 = sh[0] + sh[1] + sh[2] + sh[3];
            s2 = sh[4] + sh[5] + sh[6] + sh[7];
            float se = accs[0] * (1.0f / 9437184.0f);
            float le = accs[1] * (1.0f / 9437184.0f);
            float stop = s1 / (s2 + 16384.0f * 1e-8f);
            float dturb = stop + 0.05f * se + 0.01f * le;
            accs[2] += dturb;
            accs[3] += se;
            accs[0] = 0.0f;
            accs[1] = 0.0f;
            if (step == 5) {
                d_scal[0] = accs[2] * (1.0f / 6.0f);
                d_scal[1] = accs[3] * (1.0f / 6.0f);
            }
        }
    } else {
        if (!do_state) return;
        int b = blk;
        #pragma unroll
        for (int j = 0; j < 4; ++j) {
            int idx = tid + 256 * j;
            float s = local_acc[b * 1024 + idx];
            lp[idx] = s * (1.0f / 2304.0f);
            local_acc[b * 1024 + idx] = 0.0f;
        }
        __syncthreads();
        if (tid < 64) {
            float t = 0.0f;
            #pragma unroll
            for (int cell = 0; cell < 16; ++cell) t += lp[tid * 16 + cell];
            ps[tid] = t * (1.0f / 16.0f);
        }
        __syncthreads();
        if (tid < 64) {
            float g = gate_b[tid], v = value_b[tid];
            #pragma unroll 8
            for (int k = 0; k < 64; ++k) {
                float p = ps[k];
                g += p * gate_w[k * 64 + tid];
                v += p * value_w[k * 64 + tid];
            }
            h_state[b * 64 + tid] += sigmoid_f(g) * tanhf(v);
        }
        #pragma unroll
        for (int j = 0; j < 4; ++j) {
            int idx = tid + 256 * j;
            int co = idx >> 4, cell = idx & 15;
            float a = local_b[co];
            #pragma unroll 8
            for (int ci = 0; ci < 64; ++ci) a += local_w[co * 64 + ci] * lp[ci * 16 + cell];
            localc[b * 1024 + idx] = a;
        }
    }
}

// fused step: Laplacian + MLP + du + (norm) + probe/pool/energy accumulation
__global__ __launch_bounds__(256, 4) void main_kernel(
    const float* __restrict__ u_src, float* __restrict__ u_dst,
    const float* __restrict__ w1, const float* __restrict__ b1,
    const float* __restrict__ w2, const float* __restrict__ b2,
    const float* __restrict__ h_state, const float* __restrict__ localc,
    const float* __restrict__ norm_w,
    const float* __restrict__ p_ag, const float* __restrict__ p_al,
    const float* __restrict__ p_logdt, const float* __restrict__ diff_w,
    float* __restrict__ probe_acc, float* __restrict__ local_acc,
    float* __restrict__ accs, int do_norm) {
    __shared__ float X[64 * 64];                        // [c][px]  16384 B
    __shared__ __align__(16) unsigned short hid[64 * 130]; // [px][h] bf16, pad  16640 B
    __shared__ float lc[1024];                          // 4096 B
    __shared__ float plds[256];                         // probe partials [c][4 cells] 1024 B
    __shared__ float plocal[128];                       // local-pool partials [c][2 cells] 512 B
    __shared__ float red[256];                          // 1024 B
    __shared__ float rsum[8];

    const int tid = threadIdx.x;
    const int px = tid & 63;
    const int cg = __builtin_amdgcn_readfirstlane(tid >> 6);
    const int b = blockIdx.z;
    const int y = blockIdx.y;
    const int x0 = blockIdx.x * 64;
    const int x = x0 + px;

    const float* ub = u_src + (size_t)b * CC * HW;

    // stage X tile (float4 coalesced)
    #pragma unroll
    for (int j = 0; j < 4; ++j) {
        int f = tid + 256 * j;             // float4 index
        int c = f >> 4, xo = (f & 15) << 2;
        float4 v = *(const float4*)(ub + (size_t)c * HW + y * WW + x0 + xo);
        *(float4*)(X + c * 64 + xo) = v;
    }
    #pragma unroll
    for (int i = 0; i < 4; ++i) {
        int idx = tid + 256 * i;
        lc[idx] = localc[b * 1024 + idx];
    }
    plds[tid] = 0.0f;
    if (tid < 128) plocal[tid] = 0.0f;
    __syncthreads();

    float dt = expf(p_logdt[0]);
    dt = fminf(fmaxf(dt, 0.005f), 0.35f);
    const float a_g = softplus_f(p_ag[0]);
    const float a_l = softplus_f(p_al[0]);
    const float dw0 = diff_w[0], dw1 = diff_w[1], dw2 = diff_w[2];

    const int cbase = cg * 16;
    const int hbase = cg * 32;

    // MLP layer 1 (fp32 acc, bf16 store)
    float hacc[32];
    #pragma unroll
    for (int i = 0; i < 32; ++i) hacc[i] = 0.0f;
    #pragma unroll 4
    for (int k = 0; k < 64; ++k) {
        float xv = X[k * 64 + px];
        #pragma unroll
        for (int i = 0; i < 32; ++i) hacc[i] += xv * w1[k * HID + hbase + i];
    }
    {
        unsigned int* hid32 = (unsigned int*)hid;
        #pragma unroll
        for (int t = 0; t < 16; ++t) {
            float h0 = gelu_exact(hacc[2 * t] + b1[hbase + 2 * t]);
            float h1 = gelu_exact(hacc[2 * t + 1] + b1[hbase + 2 * t + 1]);
            unsigned int pk = ((unsigned int)f2bf(h1) << 16) | (unsigned int)f2bf(h0);
            hid32[px * 65 + (hbase >> 1) + t] = pk;
        }
    }
    __syncthreads();

    // Laplacian (overlaps with other waves' MLP compute)
    float dif[16];
    #pragma unroll
    for (int i = 0; i < 16; ++i) {
        int c = cbase + i;
        const float* up = ub + c * HW;
        float center = X[c * 64 + px];
        float l1 = stencil5(up, y, x, 1, center);
        float l4 = stencil5(up, y, x, 4, center);
        float l16 = stencil5(up, y, x, 16, center);
        dif[i] = 0.25f * (dw0 * l1 + dw1 * l4 + dw2 * l16);
    }

    // MLP layer 2 from bf16 hid
    float racc[16];
    #pragma unroll
    for (int i = 0; i < 16; ++i) racc[i] = 0.0f;
    {
        const unsigned int* hid32 = (const unsigned int*)hid;
        #pragma unroll 4
        for (int t = 0; t < 64; ++t) {
            unsigned int pk = hid32[px * 65 + t];
            float hv0 = bf2f(pk & 0xffffu);
            float hv1 = bf2f(pk >> 16);
            int h0 = 2 * t, h1 = 2 * t + 1;
            #pragma unroll
            for (int i = 0; i < 16; ++i) {
                racc[i] += hv0 * w2[h0 * CC + cbase + i];
                racc[i] += hv1 * w2[h1 * CC + cbase + i];
            }
        }
    }

    // bilinear upsample weights (in=4, out=192)
    float srcy = (y + 0.5f) * (1.0f / 48.0f) - 0.5f;
    srcy = fminf(fmaxf(srcy, 0.0f), 3.0f);
    int iy0 = (int)srcy; iy0 = min(iy0, 3);
    float ty = srcy - (float)iy0;
    int iy1 = min(iy0 + 1, 3);
    float srcx = (x + 0.5f) * (1.0f / 48.0f) - 0.5f;
    srcx = fminf(fmaxf(srcx, 0.0f), 3.0f);
    int jx0 = (int)srcx; jx0 = min(jx0, 3);
    float tx = srcx - (float)jx0;
    int jx1 = min(jx0 + 1, 3);
    const float wy0 = 1.0f - ty, wy1 = ty, wx0 = 1.0f - tx, wx1 = tx;
    const int cminp = x0 / 24;          // first probe cell in this block
    const int pcell = x / 24 - cminp;   // 0..3
    const int cx0 = x0 / 48;            // first local cell
    const int lcell = x / 48 - cx0;     // 0..1
    const int ycell = y / 48;
    const int pcy = y / 24;

    float sum_du = 0.0f, sum_df = 0.0f, csq = 0.0f;
    float candv[16];
    #pragma unroll
    for (int i = 0; i < 16; ++i) {
        int c = cbase + i;
        float react = racc[i] + b2[c];
        float hs = h_state[b * CC + c];
        const float* L = lc + c * 16;
        float upv = wy0 * (wx0 * L[iy0 * 4 + jx0] + wx1 * L[iy0 * 4 + jx1]) +
                    wy1 * (wx0 * L[iy1 * 4 + jx0] + wx1 * L[iy1 * 4 + jx1]);
        float du = dif[i] + react + a_g * hs + a_l * upv;
        float cand = X[c * 64 + px] + dt * du;
        candv[i] = cand;
        sum_du += fabsf(du);
        sum_df += fabsf(dif[i]);
        csq += cand * cand;
        // probe partial (on u_cand, PRE-norm): 8-lane segment sums
        float v = cand;
        v += __shfl_xor(v, 1);
        v += __shfl_xor(v, 2);
        v += __shfl_xor(v, 4);
        if ((px & 7) == 0) atomicAdd(&plds[c * 4 + pcell], v);
    }

    float rinv = 1.0f;
    if (do_norm) {
        red[cg * 64 + px] = csq;
        __syncthreads();
        float tot = red[px] + red[64 + px] + red[128 + px] + red[192 + px];
        rinv = 1.0f / sqrtf(tot * (1.0f / 64.0f) + 1e-8f);
    }

    float* db = u_dst + (size_t)b * CC * HW;
    #pragma unroll
    for (int i = 0; i < 16; ++i) {
        int c = cbase + i;
        float o = candv[i];
        if (do_norm) o = o * rinv * norm_w[c];
        db[c * HW + y * WW + x] = o;
        // local-pool partial (on u_next, POST-norm): 8-lane segment sums
        float v = o;
        v += __shfl_xor(v, 1);
        v += __shfl_xor(v, 2);
        v += __shfl_xor(v, 4);
        if ((px & 7) == 0) atomicAdd(&plocal[c * 2 + lcell], v);
    }

    // block-wide |du|,|diff| sums
    #pragma unroll
    for (int off = 1; off < 64; off <<= 1) {
        sum_du += __shfl_xor(sum_du, off);
        sum_df += __shfl_xor(sum_df, off);
    }
    if ((tid & 63) == 0) { rsum[cg] = sum_du; rsum[4 + cg] = sum_df; }
    __syncthreads();
    if (tid == 0) {
        atomicAdd(&accs[0], rsum[0] + rsum[1] + rsum[2] + rsum[3]);
        atomicAdd(&accs[1], rsum[4] + rsum[5] + rsum[6] + rsum[7]);
    }
    // probe flush
    {
        int c = tid >> 2, ci = tid & 3;
        int cell = cminp + ci;
        int cmaxp = (x0 + 63) / 24;
        if (cell <= cmaxp)
            atomicAdd(&probe_acc[(b * CC + c) * 64 + pcy * 8 + cell], plds[tid]);
    }
    // local-pool flush
    if (tid < 128) {
        int c = tid >> 1, ci = tid & 1;
        atomicAdd(&local_acc[(b * CC + c) * 16 + ycell * 4 + cx0 + ci], plocal[tid]);
    }
}

extern "C" void kernel_launch(void* const* d_in, const int* in_sizes, int n_in,
                              void* d_out, int out_size, void* d_ws, size_t ws_size,
                              hipStream_t stream) {
    const float* u_in    = (const float*)d_in[0];
    const float* w1      = (const float*)d_in[1];
    const float* b1      = (const float*)d_in[2];
    const float* w2      = (const float*)d_in[3];
    const float* b2      = (const float*)d_in[4];
    const float* gate_w  = (const float*)d_in[5];
    const float* gate_b  = (const float*)d_in[6];
    const float* value_w = (const float*)d_in[7];
    const float* value_b = (const float*)d_in[8];
    const float* norm_w  = (const float*)d_in[9];
    const float* local_w = (const float*)d_in[10];
    const float* local_b = (const float*)d_in[11];
    const float* p_ag    = (const float*)d_in[12];
    const float* p_al    = (const float*)d_in[13];
    const float* p_logdt = (const float*)d_in[14];
    const float* diff_w  = (const float*)d_in[15];

    float* ws = (float*)d_ws;
    float* uA         = ws;                       // USZ
    float* localc     = ws + USZ;                 // 4096
    float* prev_probe = localc + 4096;            // 16384
    // zero region (contiguous):
    float* local_acc  = prev_probe + 16384;       // 4096
    float* h_state    = local_acc + 4096;         // 256
    float* probe_acc  = h_state + 256;            // 16384
    float* accs       = probe_acc + 16384;        // 4

    float* uout   = (float*)d_out;
    float* d_scal = uout + USZ;

    zero_kernel<<<81, 256, 0, stream>>>(local_acc, 4096 + 256 + 16384 + 4);
    probe0_kernel<<<256, 256, 0, stream>>>(u_in, prev_probe);
    reduce0_kernel<<<256, 256, 0, stream>>>(u_in, local_acc);

    const float* src = u_in;
    for (int s = 0; s < 6; ++s) {
        float* dst = (s & 1) ? uout : uA;
        glue_kernel<<<5, 256, 0, stream>>>(gate_w, gate_b, value_w, value_b, local_w, local_b,
                                           h_state, localc, local_acc, prev_probe, probe_acc,
                                           accs, d_scal, 1, (s > 0) ? 1 : 0, s - 1);
        main_kernel<<<dim3(3, HH, BB), 256, 0, stream>>>(
            src, dst, w1, b1, w2, b2, h_state, localc, norm_w,
            p_ag, p_al, p_logdt, diff_w, probe_acc, local_acc, accs, (s & 1));
        src = dst;
    }
    glue_kernel<<<5, 256, 0, stream>>>(gate_w, gate_b, value_w, value_b, local_w, local_b,
                                       h_state, localc, local_acc, prev_probe, probe_acc,
                                       accs, d_scal, 0, 1, 5);
}